// Round 20
// baseline (332.234 us; speedup 1.0000x reference)
//
#include <hip/hip_runtime.h>
#include <cstddef>

#define T_DIM 30000
#define M_DIM 23
#define NJ    92
#define TILE  64      // output timesteps per conv tile
#define STR   184     // Yt stride in bf16 units (368 B)
#define SUBS  25      // sub LDS stride
#define ROWS  4       // rows per reduce block
#define NF4   1500    // float4 staged per reduce block
#define NRED  7500    // real reduce blocks
#define NCONV 469     // conv tiles
#define GRP   17      // group: 16 reduce + 1 conv
#define NBLK  (NCONV * GRP)   // 7973 blocks (reduce idx 7500..7503 dummy)

typedef short bf16x8 __attribute__((ext_vector_type(8)));
typedef float f32x4  __attribute__((ext_vector_type(4)));

__device__ __forceinline__ unsigned short f2bf(float f) {
    unsigned int u = __float_as_uint(f);
    return (unsigned short)((u + 0x7fffu + ((u >> 16) & 1u)) >> 16);
}

// One dispatch, producer-consumer. Group g: blocks 17g..17g+15 reduce rows
// [64g, 64g+64); block 17g+16 convolves tile g after spinning on cnt[g].
// Release: per-block __threadfence + atomicAdd; acquire: spin + __threadfence.
__global__ __launch_bounds__(256) void fused_k(
    const float* __restrict__ X,
    const float* __restrict__ Tau,
    const float* __restrict__ Delta,
    const float* __restrict__ W,
    const float* __restrict__ Vo,
    const float* __restrict__ C,
    const float* __restrict__ Theta,
    unsigned short* __restrict__ Yb,
    unsigned int* __restrict__ afrag,
    unsigned int* cnt,
    float* __restrict__ out)
{
    // union: reduce Xs (24000 B) | conv Yt (33856 B) + sub (6400 B)
    __shared__ __align__(16) unsigned char arena[NJ * STR * 2 + TILE * SUBS * 4];
    __shared__ float sTheta[M_DIM];
    __shared__ float sExpC[M_DIM];

    const int tid = threadIdx.x;
    const int b   = blockIdx.x;
    const int g   = b / GRP;
    const int wi  = b - g * GRP;

    if (wi < 16) {
        // ================= reduce block r =================
        const int r = 16 * g + wi;
        if (r >= NRED) return;

        float4* Xs = reinterpret_cast<float4*>(arena);
        const int lane = tid & 63, wid = tid >> 6;
        const int tb   = r * ROWS;
        const float4* Xg = reinterpret_cast<const float4*>(X) + (size_t)tb * 375;

        #pragma unroll
        for (int it = 0; it < 6; ++it) {
            int base = it * 256 + wid * 64;      // wave-uniform LDS chunk base
            int i = base + lane;
            if (i < NF4) {
                __builtin_amdgcn_global_load_lds(
                    (const __attribute__((address_space(1))) void*)(Xg + i),
                    (__attribute__((address_space(3))) void*)(Xs + base),
                    16, 0, 0);
            }
        }
        __syncthreads();

        if (tid < 92) {
            int rr = tid / 23;
            int q  = tid - 23 * rr;
            const float4* row = &Xs[rr * 375];
            float4 s = make_float4(0.f, 0.f, 0.f, 0.f);
            #pragma unroll
            for (int k = 0; k < 16; ++k) {
                float4 v = row[q + 23 * k];
                s.x += v.x; s.y += v.y; s.z += v.z; s.w += v.w;
            }
            if (q < 7) {
                float4 v = row[q + 23 * 16];
                s.x += v.x; s.y += v.y; s.z += v.z; s.w += v.w;
            }
            ushort4 o;
            o.x = f2bf(s.x); o.y = f2bf(s.y); o.z = f2bf(s.z); o.w = f2bf(s.w);
            reinterpret_cast<ushort4*>(Yb)[(size_t)(tb + rr) * 23 + q] = o;
        }

        // block 0: Toeplitz A-fragments. A_g[i,k] = Wpad_g[k-i]; frag (gg,kk):
        // lane l elem j -> i = l&15, k = kk*32 + (l>>4)*8 + j; x = k - i.
        if (b == 0) {
            for (int item = tid; item < 1024; item += 256) {
                int f = item >> 6;
                int l = item & 63;
                int gg = f >> 2, kk = f & 3;
                float eD  = __expf(Delta[0]);
                float tau = __expf(Tau[gg]);
                float wg  = W[gg];
                unsigned short vals[8];
                #pragma unroll
                for (int j = 0; j < 8; ++j) {
                    int x = kk * 32 + ((l >> 4) << 3) + j - (l & 15);
                    float val = 0.f;
                    if (x >= 0 && x <= 100) {
                        float tt  = fmaxf((float)x - eD, 0.f);
                        float tf  = tt / tau;
                        float fast = tf * __expf(-tf);
                        float kv;
                        if (gg < 2) {
                            float ts = tt / (tau * 2.8f + 10.4f);
                            kv = (fast + ts * __expf(-ts) * 0.3f) * (1.0f / 1.3f);
                        } else {
                            kv = fast;
                        }
                        val = kv * wg;
                    }
                    vals[j] = f2bf(val);
                }
                uint4 o;
                o.x = (unsigned)vals[0] | ((unsigned)vals[1] << 16);
                o.y = (unsigned)vals[2] | ((unsigned)vals[3] << 16);
                o.z = (unsigned)vals[4] | ((unsigned)vals[5] << 16);
                o.w = (unsigned)vals[6] | ((unsigned)vals[7] << 16);
                reinterpret_cast<uint4*>(afrag)[f * 64 + l] = o;
            }
        }
        __syncthreads();               // drain all global writes (vmcnt before barrier)

        if (tid == 0) {
            __threadfence();           // device-scope release of Yb (+afrag for b==0)
            int lo4 = 4 * r - 125;
            int clo = (lo4 <= 0) ? 0 : ((lo4 + 63) >> 6);
            int chi = (4 * r + 53) >> 6;
            if (chi > NCONV - 1) chi = NCONV - 1;
            for (int c2 = clo; c2 <= chi; ++c2) atomicAdd(&cnt[c2], 1u);
        }
        if (b == 0) {
            __syncthreads();           // order the fence before the broadcast bumps
            for (int i = tid; i < NCONV; i += 256) atomicAdd(&cnt[i], 1u);
        }
        return;
    }

    // ================= conv block, tile c = g =================
    const int c  = g;
    const int t0 = c * TILE;
    unsigned short* Yt = reinterpret_cast<unsigned short*>(arena);
    float* sub = reinterpret_cast<float*>(arena + NJ * STR * 2);

    if (tid < M_DIM) {
        sTheta[tid] = Theta[tid];
        sExpC[tid]  = __expf(C[tid]);
    }

    // expected producer count: reduce blocks covering rows [t0-50, t0+126) + 1 (afrag)
    int a53 = t0 - 53;
    int rlo = (a53 <= 0) ? 0 : ((a53 + 3) >> 2);
    int rhi = (t0 + 125) >> 2;
    if (rhi > NRED - 1) rhi = NRED - 1;
    const unsigned int need = (unsigned int)(rhi - rlo + 2);

    if (tid == 0) {
        while (atomicAdd(cnt + c, 0u) < need) __builtin_amdgcn_s_sleep(8);
        __threadfence();               // acquire
    }
    __syncthreads();

    // stage Yb rows [t0-50, t0+126) transposed into Yt[col'][row], col' = (cc>>2)+23*(cc&3)
    {
        unsigned int* Yw = reinterpret_cast<unsigned int*>(Yt);
        for (int i = tid; i < 88 * 23; i += 256) {
            int rp = i / 23;
            int q  = i - rp * 23;
            int g0 = t0 - 50 + 2 * rp;
            ushort4 ra = make_ushort4(0, 0, 0, 0);
            ushort4 rb = make_ushort4(0, 0, 0, 0);
            if ((unsigned)g0       < (unsigned)T_DIM) ra = reinterpret_cast<const ushort4*>(Yb)[(size_t)g0 * 23 + q];
            if ((unsigned)(g0 + 1) < (unsigned)T_DIM) rb = reinterpret_cast<const ushort4*>(Yb)[(size_t)(g0 + 1) * 23 + q];
            Yw[(q     ) * 92 + rp] = (unsigned)ra.x | ((unsigned)rb.x << 16);
            Yw[(q + 23) * 92 + rp] = (unsigned)ra.y | ((unsigned)rb.y << 16);
            Yw[(q + 46) * 92 + rp] = (unsigned)ra.z | ((unsigned)rb.z << 16);
            Yw[(q + 69) * 92 + rp] = (unsigned)ra.w | ((unsigned)rb.w << 16);
        }
    }

    const int l    = tid & 63;
    const int wave = tid >> 6;            // 0..3
    const int dt   = wave * 16;           // t-subtile
    const int n    = l & 15;
    const int kq   = (l >> 4) << 3;       // k-slot base: 0,8,16,24

    const uint4* AF = reinterpret_cast<const uint4*>(afrag);
    uint4 af[16];
    #pragma unroll
    for (int f = 0; f < 16; ++f) af[f] = AF[f * 64 + l];

    __syncthreads();

    #pragma unroll
    for (int nt = 0; nt < 2; ++nt) {
        const int m = nt * 16 + n;
        const bool mvalid = (m < M_DIM);
        const int mc = mvalid ? m : 0;

        f32x4 acc = {0.f, 0.f, 0.f, 0.f};
        #pragma unroll
        for (int gg = 0; gg < 4; ++gg) {
            // column j: j%23 == mc, j%4 == gg -> a = 3*(gg-mc) mod 4; col' = (j>>2)+23gg
            int aa = (3 * ((gg - mc) & 3)) & 3;
            int j  = mc + 23 * aa;
            int cp = (j >> 2) + 23 * gg;
            const unsigned short* colp = &Yt[cp * STR + dt + kq];

            bf16x8 b0 = *reinterpret_cast<const bf16x8*>(colp);
            acc = __builtin_amdgcn_mfma_f32_16x16x32_bf16(__builtin_bit_cast(bf16x8, af[gg*4+0]), b0, acc, 0, 0, 0);
            bf16x8 b1 = *reinterpret_cast<const bf16x8*>(colp + 32);
            acc = __builtin_amdgcn_mfma_f32_16x16x32_bf16(__builtin_bit_cast(bf16x8, af[gg*4+1]), b1, acc, 0, 0, 0);
            bf16x8 b2 = *reinterpret_cast<const bf16x8*>(colp + 64);
            acc = __builtin_amdgcn_mfma_f32_16x16x32_bf16(__builtin_bit_cast(bf16x8, af[gg*4+2]), b2, acc, 0, 0, 0);
            bf16x8 b3 = *reinterpret_cast<const bf16x8*>(colp + 96);
            acc = __builtin_amdgcn_mfma_f32_16x16x32_bf16(__builtin_bit_cast(bf16x8, af[gg*4+3]), b3, acc, 0, 0, 0);
        }

        // epilogue: D col = l&15 (m), row = (l>>4)*4 + rr -> t_local = dt + row
        if (mvalid) {
            int i0 = (l >> 4) * 4;
            #pragma unroll
            for (int rr = 0; rr < 4; ++rr)
                sub[(dt + i0 + rr) * SUBS + m] = acc[rr];
        }
    }
    __syncthreads();

    // tree cascade, one thread per timestep
    if (tid < TILE) {
        int t = t0 + tid;
        if (t < T_DIM) {
            const float* s = &sub[tid * SUBS];
            float o[M_DIM];
            #pragma unroll
            for (int mm = 11; mm < 23; ++mm) {
                float x = s[mm] - sTheta[mm];
                o[mm] = sExpC[mm] / (1.f + __expf(-x));
            }
            #pragma unroll
            for (int rr = 10; rr >= 0; --rr) {
                float x = s[rr] + o[2 * rr + 1] + o[2 * rr + 2] - sTheta[rr];
                o[rr] = sExpC[rr] / (1.f + __expf(-x));
            }
            out[t] = o[0] + Vo[0];
        }
    }
}

extern "C" void kernel_launch(void* const* d_in, const int* in_sizes, int n_in,
                              void* d_out, int out_size, void* d_ws, size_t ws_size,
                              hipStream_t stream) {
    const float* X     = (const float*)d_in[0];
    const float* Vo    = (const float*)d_in[1];
    const float* Tau   = (const float*)d_in[2];
    const float* Delta = (const float*)d_in[3];
    const float* W     = (const float*)d_in[4];
    const float* C     = (const float*)d_in[5];
    const float* Theta = (const float*)d_in[6];
    float* out = (float*)d_out;

    unsigned short* Yb  = (unsigned short*)d_ws;                                  // 5.52 MB
    unsigned int* afrag = (unsigned int*)((char*)d_ws + (size_t)T_DIM * NJ * 2);  // 16 KB
    unsigned int* cnt   = (unsigned int*)((char*)afrag + 16384);                  // 1876 B

    hipMemsetAsync(cnt, 0, NCONV * sizeof(unsigned int), stream);
    fused_k<<<NBLK, 256, 0, stream>>>(X, Tau, Delta, W, Vo, C, Theta,
                                      Yb, afrag, cnt, out);
}

// Round 21
// 312.675 us; speedup vs baseline: 1.0626x; 1.0626x over previous
//
#include <hip/hip_runtime.h>
#include <cstddef>

#define T_DIM 30000
#define M_DIM 23
#define NJ    92
#define TILE  32        // output timesteps per conv tile
#define YSTR  152       // Yt col stride in bf16 (144 staged rows + 8 pad)
#define SUBS  25        // sub LDS stride
#define ROWS  4         // rows per reduce block
#define NF4   1500      // float4 staged per reduce block
#define NRED  7500      // real reduce blocks
#define NG    938       // groups = conv tiles (938*32 = 30016)
#define GRP   9         // 8 reduce + 1 conv per group
#define NBLK  (NG * GRP)
#define CSTRD 16        // cnt stride in dwords (64 B -> no line sharing)

typedef short bf16x8 __attribute__((ext_vector_type(8)));
typedef float f32x4  __attribute__((ext_vector_type(4)));

__device__ __forceinline__ unsigned short f2bf(float f) {
    unsigned int u = __float_as_uint(f);
    return (unsigned short)((u + 0x7fffu + ((u >> 16) & 1u)) >> 16);
}

// One dispatch. Group g: blocks 9g..9g+7 reduce rows [32g, 32g+32);
// block 9g+8 convolves tile g after groups g-2..g+2 complete (1 atomicAdd per
// reduce block to its own padded group counter; conv spins 5 counters + flag).
__global__ __launch_bounds__(256, 4) void fused_k(
    const float* __restrict__ X,
    const float* __restrict__ Tau,
    const float* __restrict__ Delta,
    const float* __restrict__ W,
    const float* __restrict__ Vo,
    const float* __restrict__ C,
    const float* __restrict__ Theta,
    unsigned short* __restrict__ Yb,
    unsigned int* __restrict__ afrag,
    unsigned int* cnt,
    float* __restrict__ out)
{
    // union: reduce Xs (24000 B) | conv Yt (27968 B) + sub (3200 B)
    __shared__ __align__(16) unsigned char arena[NJ * YSTR * 2 + TILE * SUBS * 4];
    __shared__ float sTheta[M_DIM];
    __shared__ float sExpC[M_DIM];

    const int tid = threadIdx.x;
    const int b   = blockIdx.x;
    const int g   = b / GRP;
    const int wi  = b - g * GRP;

    if (wi < 8) {
        // ================= reduce block r (R19-proven body) =================
        const int r = 8 * g + wi;
        if (r >= NRED) {                       // 4 dummy slots in last group
            if (tid == 0) atomicAdd(&cnt[g * CSTRD], 1u);
            return;
        }

        float4* Xs = reinterpret_cast<float4*>(arena);
        const int lane = tid & 63, wid = tid >> 6;
        const int tb   = r * ROWS;
        const float4* Xg = reinterpret_cast<const float4*>(X) + (size_t)tb * 375;

        #pragma unroll
        for (int it = 0; it < 6; ++it) {
            int base = it * 256 + wid * 64;    // wave-uniform LDS chunk base
            int i = base + lane;
            if (i < NF4) {
                __builtin_amdgcn_global_load_lds(
                    (const __attribute__((address_space(1))) void*)(Xg + i),
                    (__attribute__((address_space(3))) void*)(Xs + base),
                    16, 0, 0);
            }
        }
        __syncthreads();

        if (tid < 92) {
            int rr = tid / 23;
            int q  = tid - 23 * rr;
            const float4* row = &Xs[rr * 375];
            float4 s = make_float4(0.f, 0.f, 0.f, 0.f);
            #pragma unroll
            for (int k = 0; k < 16; ++k) {
                float4 v = row[q + 23 * k];
                s.x += v.x; s.y += v.y; s.z += v.z; s.w += v.w;
            }
            if (q < 7) {
                float4 v = row[q + 23 * 16];
                s.x += v.x; s.y += v.y; s.z += v.z; s.w += v.w;
            }
            ushort4 o;
            o.x = f2bf(s.x); o.y = f2bf(s.y); o.z = f2bf(s.z); o.w = f2bf(s.w);
            reinterpret_cast<ushort4*>(Yb)[(size_t)(tb + rr) * 23 + q] = o;
        }

        // block 0: Toeplitz A-fragments. A_g[i,k] = Wpad_g[k-i]; frag (gg,kk):
        // lane l elem j -> i = l&15, k = kk*32 + (l>>4)*8 + j; x = k - i.
        if (b == 0) {
            for (int item = tid; item < 1024; item += 256) {
                int f = item >> 6;
                int l = item & 63;
                int gg = f >> 2, kk = f & 3;
                float eD  = __expf(Delta[0]);
                float tau = __expf(Tau[gg]);
                float wg  = W[gg];
                unsigned short vals[8];
                #pragma unroll
                for (int j = 0; j < 8; ++j) {
                    int x = kk * 32 + ((l >> 4) << 3) + j - (l & 15);
                    float val = 0.f;
                    if (x >= 0 && x <= 100) {
                        float tt  = fmaxf((float)x - eD, 0.f);
                        float tf  = tt / tau;
                        float fast = tf * __expf(-tf);
                        float kv;
                        if (gg < 2) {
                            float ts = tt / (tau * 2.8f + 10.4f);
                            kv = (fast + ts * __expf(-ts) * 0.3f) * (1.0f / 1.3f);
                        } else {
                            kv = fast;
                        }
                        val = kv * wg;
                    }
                    vals[j] = f2bf(val);
                }
                uint4 o;
                o.x = (unsigned)vals[0] | ((unsigned)vals[1] << 16);
                o.y = (unsigned)vals[2] | ((unsigned)vals[3] << 16);
                o.z = (unsigned)vals[4] | ((unsigned)vals[5] << 16);
                o.w = (unsigned)vals[6] | ((unsigned)vals[7] << 16);
                reinterpret_cast<uint4*>(afrag)[f * 64 + l] = o;
            }
        }
        __syncthreads();                       // barrier drains vmcnt (writes done)

        if (tid == 0) {
            __threadfence();                   // device-scope release of Yb (+afrag)
            atomicAdd(&cnt[g * CSTRD], 1u);    // ONE add per block
            if (b == 0) atomicExch(&cnt[NG * CSTRD], 1u);   // afrag-ready flag
        }
        return;
    }

    // ================= conv block, tile c = g =================
    const int c  = g;
    const int t0 = c * TILE;

    if (tid == 0) {
        int glo = (c >= 2) ? c - 2 : 0;
        int ghi = (c + 2 <= NG - 1) ? c + 2 : NG - 1;
        for (;;) {
            bool ok = atomicAdd(&cnt[NG * CSTRD], 0u) != 0u;
            for (int G = glo; ok && G <= ghi; ++G)
                ok = (atomicAdd(&cnt[G * CSTRD], 0u) >= 8u);
            if (ok) break;
            __builtin_amdgcn_s_sleep(16);
        }
        __threadfence();                       // acquire
    }
    __syncthreads();

    unsigned short* Yt = reinterpret_cast<unsigned short*>(arena);
    float* sub = reinterpret_cast<float*>(arena + NJ * YSTR * 2);

    if (tid < M_DIM) {
        sTheta[tid] = Theta[tid];
        sExpC[tid]  = __expf(C[tid]);
    }

    // stage Yb rows [t0-50, t0+94) transposed into Yt[col'][row] (72 pairs),
    // col' = (cc>>2) + 23*(cc&3); row pairs packed into dwords.
    {
        unsigned int* Yw = reinterpret_cast<unsigned int*>(Yt);
        for (int i = tid; i < 72 * 23; i += 256) {
            int rp = i / 23;
            int q  = i - rp * 23;
            int g0 = t0 - 50 + 2 * rp;
            ushort4 ra = make_ushort4(0, 0, 0, 0);
            ushort4 rb = make_ushort4(0, 0, 0, 0);
            if ((unsigned)g0       < (unsigned)T_DIM) ra = reinterpret_cast<const ushort4*>(Yb)[(size_t)g0 * 23 + q];
            if ((unsigned)(g0 + 1) < (unsigned)T_DIM) rb = reinterpret_cast<const ushort4*>(Yb)[(size_t)(g0 + 1) * 23 + q];
            Yw[(q     ) * 76 + rp] = (unsigned)ra.x | ((unsigned)rb.x << 16);
            Yw[(q + 23) * 76 + rp] = (unsigned)ra.y | ((unsigned)rb.y << 16);
            Yw[(q + 46) * 76 + rp] = (unsigned)ra.z | ((unsigned)rb.z << 16);
            Yw[(q + 69) * 76 + rp] = (unsigned)ra.w | ((unsigned)rb.w << 16);
        }
    }

    const int l    = tid & 63;
    const int wave = tid >> 6;            // 0..3
    const int dt   = (wave & 1) * 16;     // t-subtile
    const int nt   = wave >> 1;           // m-tile
    const int n    = l & 15;
    const int m    = nt * 16 + n;
    const bool mvalid = (m < M_DIM);
    const int mc   = mvalid ? m : 0;
    const int kq   = (l >> 4) << 3;       // k-slot base: 0,8,16,24

    const uint4* AF = reinterpret_cast<const uint4*>(afrag);
    uint4 af[16];
    #pragma unroll
    for (int f = 0; f < 16; ++f) af[f] = AF[f * 64 + l];

    __syncthreads();

    f32x4 acc = {0.f, 0.f, 0.f, 0.f};
    #pragma unroll
    for (int gg = 0; gg < 4; ++gg) {
        // column j: j%23 == mc, j%4 == gg -> a = 3*(gg-mc) mod 4; col' = (j>>2)+23gg
        int aa = (3 * ((gg - mc) & 3)) & 3;
        int j  = mc + 23 * aa;
        int cp = (j >> 2) + 23 * gg;
        const unsigned short* colp = &Yt[cp * YSTR + dt + kq];

        bf16x8 b0 = *reinterpret_cast<const bf16x8*>(colp);
        acc = __builtin_amdgcn_mfma_f32_16x16x32_bf16(__builtin_bit_cast(bf16x8, af[gg*4+0]), b0, acc, 0, 0, 0);
        bf16x8 b1 = *reinterpret_cast<const bf16x8*>(colp + 32);
        acc = __builtin_amdgcn_mfma_f32_16x16x32_bf16(__builtin_bit_cast(bf16x8, af[gg*4+1]), b1, acc, 0, 0, 0);
        bf16x8 b2 = *reinterpret_cast<const bf16x8*>(colp + 64);
        acc = __builtin_amdgcn_mfma_f32_16x16x32_bf16(__builtin_bit_cast(bf16x8, af[gg*4+2]), b2, acc, 0, 0, 0);
        bf16x8 b3 = *reinterpret_cast<const bf16x8*>(colp + 96);
        acc = __builtin_amdgcn_mfma_f32_16x16x32_bf16(__builtin_bit_cast(bf16x8, af[gg*4+3]), b3, acc, 0, 0, 0);
    }

    // epilogue: D col = l&15 (m), row = (l>>4)*4 + rr -> t_local = dt + row
    if (mvalid) {
        int i0 = (l >> 4) * 4;
        #pragma unroll
        for (int rr = 0; rr < 4; ++rr)
            sub[(dt + i0 + rr) * SUBS + m] = acc[rr];
    }
    __syncthreads();

    // tree cascade, one thread per timestep
    if (tid < TILE) {
        int t = t0 + tid;
        if (t < T_DIM) {
            const float* s = &sub[tid * SUBS];
            float o[M_DIM];
            #pragma unroll
            for (int mm = 11; mm < 23; ++mm) {
                float x = s[mm] - sTheta[mm];
                o[mm] = sExpC[mm] / (1.f + __expf(-x));
            }
            #pragma unroll
            for (int rr = 10; rr >= 0; --rr) {
                float x = s[rr] + o[2 * rr + 1] + o[2 * rr + 2] - sTheta[rr];
                o[rr] = sExpC[rr] / (1.f + __expf(-x));
            }
            out[t] = o[0] + Vo[0];
        }
    }
}

extern "C" void kernel_launch(void* const* d_in, const int* in_sizes, int n_in,
                              void* d_out, int out_size, void* d_ws, size_t ws_size,
                              hipStream_t stream) {
    const float* X     = (const float*)d_in[0];
    const float* Vo    = (const float*)d_in[1];
    const float* Tau   = (const float*)d_in[2];
    const float* Delta = (const float*)d_in[3];
    const float* W     = (const float*)d_in[4];
    const float* C     = (const float*)d_in[5];
    const float* Theta = (const float*)d_in[6];
    float* out = (float*)d_out;

    unsigned short* Yb  = (unsigned short*)d_ws;                                  // 5.52 MB
    unsigned int* afrag = (unsigned int*)((char*)d_ws + (size_t)T_DIM * NJ * 2);  // 16 KB
    unsigned int* cnt   = (unsigned int*)((char*)afrag + 16384);                  // ~60 KB

    hipMemsetAsync(cnt, 0, (NG * CSTRD + 1) * sizeof(unsigned int), stream);
    fused_k<<<NBLK, 256, 0, stream>>>(X, Tau, Delta, W, Vo, C, Theta,
                                      Yb, afrag, cnt, out);
}

// Round 22
// 38.286 us; speedup vs baseline: 8.6776x; 8.1668x over previous
//
#include <hip/hip_runtime.h>
#include <cstddef>

#define T_DIM 30000
#define M_DIM 23
#define NJ    92
#define TILE  64      // output timesteps per conv block
#define STR   184     // Yt stride in bf16 units (368 B)
#define SUBS  25      // sub LDS stride
#define XP4   377     // reduce LDS pitch in float4

typedef short bf16x8 __attribute__((ext_vector_type(8)));
typedef float f32x4  __attribute__((ext_vector_type(4)));

__device__ __forceinline__ unsigned short f2bf(float f) {
    unsigned int u = __float_as_uint(f);
    return (unsigned short)((u + 0x7fffu + ((u >> 16) & 1u)) >> 16);
}

// ---- Kernel B: X (T,1500) fp32 -> Yb (T,92) bf16 ; Yb[t,j] = sum_{n%92==j} X[t,n]
// High-TLP: 2 rows per 128-thread block. Block 0 additionally writes the
// Toeplitz A-fragment table (1024 x 16B) used by the conv kernel.
__global__ __launch_bounds__(128) void reduce_k(const float* __restrict__ X,
                                                const float* __restrict__ Tau,
                                                const float* __restrict__ Delta,
                                                const float* __restrict__ W,
                                                unsigned short* __restrict__ Yb,
                                                unsigned int* __restrict__ afrag) {
    __shared__ __align__(16) float4 Xs[2 * XP4];   // 12064 B

    const int tid = threadIdx.x;
    const int tb  = blockIdx.x * 2;                // 15000 blocks x 2 rows

    const float4* Xg = reinterpret_cast<const float4*>(X) + (size_t)tb * 375;
    #pragma unroll
    for (int it = 0; it < 6; ++it) {
        int i = tid + 128 * it;
        if (i < 750) {
            int r = (i >= 375) ? 1 : 0;
            int pos = i - r * 375;
            Xs[r * XP4 + pos] = Xg[i];
        }
    }
    __syncthreads();

    if (tid < 46) {
        int r = tid / 23;
        int q = tid - 23 * r;
        const float4* row = &Xs[r * XP4];
        float4 s = make_float4(0.f, 0.f, 0.f, 0.f);
        #pragma unroll
        for (int k = 0; k < 16; ++k) {
            float4 v = row[q + 23 * k];
            s.x += v.x; s.y += v.y; s.z += v.z; s.w += v.w;
        }
        if (q < 7) {
            float4 v = row[q + 23 * 16];
            s.x += v.x; s.y += v.y; s.z += v.z; s.w += v.w;
        }
        ushort4 o;
        o.x = f2bf(s.x); o.y = f2bf(s.y); o.z = f2bf(s.z); o.w = f2bf(s.w);
        reinterpret_cast<ushort4*>(Yb)[(size_t)(tb + r) * 23 + q] = o;
    }

    // block 0: Toeplitz A-fragments. A_g[i,k] = Wpad_g[k-i]; frag (g,kk):
    // lane l elem j -> i = l&15, k = kk*32 + (l>>4)*8 + j; x = k - i.
    if (blockIdx.x == 0) {
        for (int item = tid; item < 1024; item += 128) {
            int f = item >> 6;
            int l = item & 63;
            int g = f >> 2, kk = f & 3;
            float eD  = __expf(Delta[0]);
            float tau = __expf(Tau[g]);
            float wg  = W[g];
            unsigned short vals[8];
            #pragma unroll
            for (int j = 0; j < 8; ++j) {
                int x = kk * 32 + ((l >> 4) << 3) + j - (l & 15);
                float val = 0.f;
                if (x >= 0 && x <= 100) {
                    float tt  = fmaxf((float)x - eD, 0.f);
                    float tf  = tt / tau;
                    float fast = tf * __expf(-tf);
                    float kv;
                    if (g < 2) {
                        float ts = tt / (tau * 2.8f + 10.4f);
                        kv = (fast + ts * __expf(-ts) * 0.3f) * (1.0f / 1.3f);
                    } else {
                        kv = fast;
                    }
                    val = kv * wg;
                }
                vals[j] = f2bf(val);
            }
            uint4 o;
            o.x = (unsigned)vals[0] | ((unsigned)vals[1] << 16);
            o.y = (unsigned)vals[2] | ((unsigned)vals[3] << 16);
            o.z = (unsigned)vals[4] | ((unsigned)vals[5] << 16);
            o.w = (unsigned)vals[6] | ((unsigned)vals[7] << 16);
            reinterpret_cast<uint4*>(afrag)[f * 64 + l] = o;
        }
    }
}

// ---- Kernel C: MFMA Toeplitz conv + tree cascade (R9 structure: global af).
// 512 threads = 8 waves: wave -> (dt = (w&3)*16, nt = w>>2).
__global__ __launch_bounds__(512, 4) void conv_tree_k(
    const unsigned short* __restrict__ Yb,
    const unsigned int* __restrict__ afrag,
    const float* __restrict__ Vo,
    const float* __restrict__ C,
    const float* __restrict__ Theta,
    float* __restrict__ out)
{
    __shared__ __align__(16) unsigned short Yt[NJ * STR];  // 33856 B, col-major
    __shared__ float sub[TILE * SUBS];                     // 6400 B
    __shared__ float sTheta[M_DIM];
    __shared__ float sExpC[M_DIM];

    const int tid = threadIdx.x;
    const int t0  = blockIdx.x * TILE;

    if (tid < M_DIM) {
        sTheta[tid] = Theta[tid];
        sExpC[tid]  = __expf(C[tid]);
    }

    // --- stage Yb rows [t0-50, t0+126) transposed into Yt[col'][r] (bf16),
    //     col' = (c>>2) + 23*(c&3); row pairs packed into dwords. 88 pairs.
    {
        unsigned int* Yw = reinterpret_cast<unsigned int*>(Yt);
        for (int i = tid; i < 88 * 23; i += 512) {
            int rp = i / 23;
            int q  = i - rp * 23;
            int g0 = t0 - 50 + 2 * rp;
            ushort4 ra = make_ushort4(0, 0, 0, 0);
            ushort4 rb = make_ushort4(0, 0, 0, 0);
            if ((unsigned)g0       < (unsigned)T_DIM) ra = reinterpret_cast<const ushort4*>(Yb)[(size_t)g0 * 23 + q];
            if ((unsigned)(g0 + 1) < (unsigned)T_DIM) rb = reinterpret_cast<const ushort4*>(Yb)[(size_t)(g0 + 1) * 23 + q];
            Yw[(q     ) * 92 + rp] = (unsigned)ra.x | ((unsigned)rb.x << 16);
            Yw[(q + 23) * 92 + rp] = (unsigned)ra.y | ((unsigned)rb.y << 16);
            Yw[(q + 46) * 92 + rp] = (unsigned)ra.z | ((unsigned)rb.z << 16);
            Yw[(q + 69) * 92 + rp] = (unsigned)ra.w | ((unsigned)rb.w << 16);
        }
    }

    const int l    = tid & 63;
    const int wave = tid >> 6;            // 0..7
    const int dt   = (wave & 3) * 16;     // t-subtile
    const int nt   = wave >> 2;           // m-tile (0: m 0-15, 1: m 16-22)
    const int n    = l & 15;
    const int m    = nt * 16 + n;
    const bool mvalid = (m < M_DIM);
    const int mc   = mvalid ? m : 0;
    const int kq   = (l >> 4) << 3;       // k-slot base: 0,8,16,24

    __syncthreads();

    f32x4 acc = {0.f, 0.f, 0.f, 0.f};
    const uint4* AF = reinterpret_cast<const uint4*>(afrag);

    #pragma unroll
    for (int g = 0; g < 4; ++g) {
        // column j: j%23 == mc, j%4 == g -> a = 3*(g-mc) mod 4; col' = (j>>2) + 23g
        int a  = (3 * ((g - mc) & 3)) & 3;
        int j  = mc + 23 * a;
        int cp = (j >> 2) + 23 * g;
        const unsigned short* colp = &Yt[cp * STR + dt + kq];

        uint4 a0 = AF[(g * 4 + 0) * 64 + l];
        uint4 a1 = AF[(g * 4 + 1) * 64 + l];
        uint4 a2 = AF[(g * 4 + 2) * 64 + l];
        uint4 a3 = AF[(g * 4 + 3) * 64 + l];

        bf16x8 b0 = *reinterpret_cast<const bf16x8*>(colp);
        acc = __builtin_amdgcn_mfma_f32_16x16x32_bf16(__builtin_bit_cast(bf16x8, a0), b0, acc, 0, 0, 0);
        bf16x8 b1 = *reinterpret_cast<const bf16x8*>(colp + 32);
        acc = __builtin_amdgcn_mfma_f32_16x16x32_bf16(__builtin_bit_cast(bf16x8, a1), b1, acc, 0, 0, 0);
        bf16x8 b2 = *reinterpret_cast<const bf16x8*>(colp + 64);
        acc = __builtin_amdgcn_mfma_f32_16x16x32_bf16(__builtin_bit_cast(bf16x8, a2), b2, acc, 0, 0, 0);
        bf16x8 b3 = *reinterpret_cast<const bf16x8*>(colp + 96);
        acc = __builtin_amdgcn_mfma_f32_16x16x32_bf16(__builtin_bit_cast(bf16x8, a3), b3, acc, 0, 0, 0);
    }

    // epilogue: D col = l&15, row = (l>>4)*4 + r  ->  t_local = dt + row, m-col
    if (mvalid) {
        int i0 = (l >> 4) * 4;
        #pragma unroll
        for (int r = 0; r < 4; ++r)
            sub[(dt + i0 + r) * SUBS + m] = acc[r];
    }
    __syncthreads();

    // --- tree cascade, one thread per timestep
    if (tid < TILE) {
        int t = t0 + tid;
        if (t < T_DIM) {
            const float* s = &sub[tid * SUBS];
            float o[M_DIM];
            #pragma unroll
            for (int mm = 11; mm < 23; ++mm) {
                float x = s[mm] - sTheta[mm];
                o[mm] = sExpC[mm] / (1.f + __expf(-x));
            }
            #pragma unroll
            for (int rr = 10; rr >= 0; --rr) {
                float x = s[rr] + o[2 * rr + 1] + o[2 * rr + 2] - sTheta[rr];
                o[rr] = sExpC[rr] / (1.f + __expf(-x));
            }
            out[t] = o[0] + Vo[0];
        }
    }
}

extern "C" void kernel_launch(void* const* d_in, const int* in_sizes, int n_in,
                              void* d_out, int out_size, void* d_ws, size_t ws_size,
                              hipStream_t stream) {
    const float* X     = (const float*)d_in[0];
    const float* Vo    = (const float*)d_in[1];
    const float* Tau   = (const float*)d_in[2];
    const float* Delta = (const float*)d_in[3];
    const float* W     = (const float*)d_in[4];
    const float* C     = (const float*)d_in[5];
    const float* Theta = (const float*)d_in[6];
    float* out = (float*)d_out;

    unsigned short* Yb  = (unsigned short*)d_ws;                                  // 5.52 MB
    unsigned int* afrag = (unsigned int*)((char*)d_ws + (size_t)T_DIM * NJ * 2);  // 16 KB

    reduce_k<<<T_DIM / 2, 128, 0, stream>>>(X, Tau, Delta, W, Yb, afrag);
    conv_tree_k<<<(T_DIM + TILE - 1) / TILE, 512, 0, stream>>>(
        Yb, afrag, Vo, C, Theta, out);
}